// Round 2
// baseline (900.151 us; speedup 1.0000x reference)
//
#include <hip/hip_runtime.h>
#include <hip/hip_bf16.h>
#include <type_traits>

// ---------- helpers ----------
typedef __attribute__((ext_vector_type(8))) __bf16 bf16x8;
typedef __attribute__((ext_vector_type(4))) float f32x4;

__device__ __forceinline__ float b2f(unsigned short u) {
    unsigned int x = ((unsigned int)u) << 16;
    float f;
    __builtin_memcpy(&f, &x, 4);
    return f;
}
__device__ __forceinline__ unsigned short f2b(float f) {
    __hip_bfloat16 h = __float2bfloat16(f);
    unsigned short u;
    __builtin_memcpy(&u, &h, 2);
    return u;
}
union U4 { uint4 v; unsigned short u[8]; };

// ---------- 512x512 transpose + f32->bf16 convert (for W matrices) ----------
__global__ __launch_bounds__(256) void transpose512cvt(const float* __restrict__ in,
                                                       unsigned short* __restrict__ out)
{
    __shared__ float tile[32][33];
    int tx = threadIdx.x & 31, ty = threadIdx.x >> 5;
    int bx = blockIdx.x, by = blockIdx.y;
    #pragma unroll
    for (int i = 0; i < 32; i += 8)
        tile[ty + i][tx] = in[(size_t)(bx * 32 + ty + i) * 512 + by * 32 + tx];
    __syncthreads();
    #pragma unroll
    for (int i = 0; i < 32; i += 8)
        out[(size_t)(by * 32 + ty + i) * 512 + bx * 32 + tx] = f2b(tile[tx][ty + i]);
}

// ---------- GEMM: C[M,N] = A[M,512] @ Bt[N,512]^T + bias ----------
// A: f32 or bf16 (converted to bf16 during LDS staging). Bt: bf16. C: f32 or bf16.
// 64x64 tile per 256-thread block (4 waves), MFMA 16x16x32 bf16, fp32 acc.
#define GLDK 40  // 32 + 8 pad (bf16 elems); row stride 80 B (16B-aligned)

template<typename TA, typename TC>
__global__ __launch_bounds__(256) void gemm_bt(
    const TA* __restrict__ A,
    const unsigned short* __restrict__ Bt,
    const float* __restrict__ bias,
    TC* __restrict__ C,
    int M, int N)
{
    const int K = 512;
    __shared__ __align__(16) unsigned short As[64 * GLDK];
    __shared__ __align__(16) unsigned short Bs[64 * GLDK];
    int m0 = blockIdx.x * 64, n0 = blockIdx.y * 64;
    int t = threadIdx.x;
    int wave = t >> 6, lane = t & 63, quad = lane >> 4, l16 = lane & 15;

    f32x4 acc[4];
    #pragma unroll
    for (int c = 0; c < 4; ++c) acc[c] = (f32x4){0.f, 0.f, 0.f, 0.f};

    int ar = t >> 2, ac = (t & 3) * 8;
    const TA* Ap = A + (size_t)(m0 + ar) * K + ac;
    const unsigned short* Bp = Bt + (size_t)(n0 + ar) * K + ac;
    unsigned short* AsW = &As[ar * GLDK + ac];
    unsigned short* BsW = &Bs[ar * GLDK + ac];

    for (int k0 = 0; k0 < K; k0 += 32) {
        U4 av;
        if constexpr (std::is_same<TA, float>::value) {
            const float4* Af = (const float4*)(Ap + k0);
            float4 f0 = Af[0], f1 = Af[1];
            av.u[0] = f2b(f0.x); av.u[1] = f2b(f0.y); av.u[2] = f2b(f0.z); av.u[3] = f2b(f0.w);
            av.u[4] = f2b(f1.x); av.u[5] = f2b(f1.y); av.u[6] = f2b(f1.z); av.u[7] = f2b(f1.w);
        } else {
            av.v = *(const uint4*)((const unsigned short*)Ap + k0);
        }
        uint4 bv = *(const uint4*)(Bp + k0);
        __syncthreads();
        *(uint4*)AsW = av.v;
        *(uint4*)BsW = bv;
        __syncthreads();
        bf16x8 af = *(const bf16x8*)&As[(wave * 16 + l16) * GLDK + quad * 8];
        #pragma unroll
        for (int c = 0; c < 4; ++c) {
            bf16x8 bf = *(const bf16x8*)&Bs[(c * 16 + l16) * GLDK + quad * 8];
            acc[c] = __builtin_amdgcn_mfma_f32_16x16x32_bf16(af, bf, acc[c], 0, 0, 0);
        }
    }
    // C/D layout (verified m89/m91): col = lane&15, row = (lane>>4)*4 + reg
    int row_base = m0 + wave * 16 + quad * 4;
    #pragma unroll
    for (int c = 0; c < 4; ++c) {
        int col = n0 + c * 16 + l16;
        float bc = bias[col];
        #pragma unroll
        for (int i = 0; i < 4; ++i) {
            float v = acc[c][i] + bc;
            if constexpr (std::is_same<TC, float>::value)
                C[(size_t)(row_base + i) * N + col] = v;
            else
                C[(size_t)(row_base + i) * N + col] = __float2bfloat16(v);
        }
    }
}

// ---------- temporal attention: one block per (b,s) ----------
// scores [h,m] x [24 keys], softmax over 24, qkv row [64] per (h,m).
__global__ __launch_bounds__(256) void temporal_attn(
    const __hip_bfloat16* __restrict__ Qt, const __hip_bfloat16* __restrict__ Kt,
    const __hip_bfloat16* __restrict__ Vt, const __hip_bfloat16* __restrict__ Ksp,
    const __hip_bfloat16* __restrict__ Vsp,
    const int* __restrict__ mask_t, const int* __restrict__ mask_s,
    float* __restrict__ w_t_out, __hip_bfloat16* __restrict__ qkv_t)
{
    int bs = blockIdx.x;
    int b = bs >> 9, s = bs & 511;
    __shared__ __align__(16) unsigned short sK[8 * 520];
    __shared__ __align__(16) unsigned short sKs[16 * 520];
    __shared__ float wbuf[64 * 24];
    __shared__ float maskadd[24];
    int t = threadIdx.x;

    const uint4* Kg = (const uint4*)((const unsigned short*)Kt + (size_t)bs * 4096);
    for (int idx = t; idx < 512; idx += 256) {
        uint4 v = Kg[idx];
        *(uint4*)&sK[(idx >> 6) * 520 + (idx & 63) * 8] = v;
    }
    const uint4* Ksg = (const uint4*)((const unsigned short*)Ksp + (size_t)b * 8192);
    for (int idx = t; idx < 1024; idx += 256) {
        uint4 v = Ksg[idx];
        *(uint4*)&sKs[(idx >> 6) * 520 + (idx & 63) * 8] = v;
    }
    if (t < 8) maskadd[t] = mask_t[bs * 8 + t] ? 0.f : -1e30f;
    else if (t < 24) maskadd[t] = mask_s[b * 16 + (t - 8)] ? 0.f : -1e30f;

    int p = t >> 2, j = t & 3;       // pair p = (h,m), 4 threads per pair
    int h = p >> 3, m = p & 7;

    float qreg[64];
    {
        const uint4* qp = (const uint4*)((const unsigned short*)Qt + (size_t)bs * 4096 + (size_t)m * 512 + h * 64);
        #pragma unroll
        for (int i = 0; i < 8; ++i) {
            U4 u; u.v = qp[i];
            #pragma unroll
            for (int k = 0; k < 8; ++k) qreg[i * 8 + k] = b2f(u.u[k]);
        }
    }
    __syncthreads();

    float sc[6];
    #pragma unroll
    for (int i = 0; i < 6; ++i) {
        int n = j + i * 4;
        const unsigned short* krow = (n < 8) ? &sK[n * 520 + h * 64] : &sKs[(n - 8) * 520 + h * 64];
        float acc = 0.f;
        #pragma unroll
        for (int d = 0; d < 64; ++d) acc += qreg[d] * b2f(krow[d]);
        sc[i] = acc * 0.125f + maskadd[n];
    }
    float mx = sc[0];
    #pragma unroll
    for (int i = 1; i < 6; ++i) mx = fmaxf(mx, sc[i]);
    mx = fmaxf(mx, __shfl_xor(mx, 1));
    mx = fmaxf(mx, __shfl_xor(mx, 2));
    float e[6], se = 0.f;
    #pragma unroll
    for (int i = 0; i < 6; ++i) { e[i] = __expf(sc[i] - mx); se += e[i]; }
    se += __shfl_xor(se, 1);
    se += __shfl_xor(se, 2);
    float inv = 1.f / se;
    size_t wtb = ((((size_t)b * 8 + h) * 512 + s) * 8 + m) * 24;
    #pragma unroll
    for (int i = 0; i < 6; ++i) {
        int n = j + i * 4;
        float w = e[i] * inv;
        wbuf[p * 24 + n] = w;
        w_t_out[wtb + n] = w;
    }
    __syncthreads();

    // phase 2: qkv[h,m][d0..d0+16] = sum_n w[n] * V[n][d]
    int hm = t >> 2, dc = t & 3;
    int h2 = hm >> 3, m2 = hm & 7, d0 = dc * 16;
    float acc2[16];
    #pragma unroll
    for (int i = 0; i < 16; ++i) acc2[i] = 0.f;
    const unsigned short* Vb = (const unsigned short*)Vt + (size_t)bs * 4096 + h2 * 64 + d0;
    #pragma unroll
    for (int n = 0; n < 8; ++n) {
        float wv = wbuf[hm * 24 + n];
        U4 a, c;
        a.v = *(const uint4*)(Vb + n * 512);
        c.v = *(const uint4*)(Vb + n * 512 + 8);
        #pragma unroll
        for (int i = 0; i < 8; ++i) { acc2[i] += wv * b2f(a.u[i]); acc2[8 + i] += wv * b2f(c.u[i]); }
    }
    const unsigned short* Vsb = (const unsigned short*)Vsp + (size_t)b * 8192 + h2 * 64 + d0;
    #pragma unroll
    for (int n = 0; n < 16; ++n) {
        float wv = wbuf[hm * 24 + 8 + n];
        U4 a, c;
        a.v = *(const uint4*)(Vsb + n * 512);
        c.v = *(const uint4*)(Vsb + n * 512 + 8);
        #pragma unroll
        for (int i = 0; i < 8; ++i) { acc2[i] += wv * b2f(a.u[i]); acc2[8 + i] += wv * b2f(c.u[i]); }
    }
    unsigned short* op = (unsigned short*)qkv_t + (size_t)bs * 4096 + (size_t)m2 * 512 + h2 * 64 + d0;
    #pragma unroll
    for (int i = 0; i < 16; ++i) op[i] = f2b(acc2[i]);
}

// ---------- static attention: one block per (b,h,q); softmax over 4112 keys ----------
__global__ __launch_bounds__(256) void static_attn(
    const __hip_bfloat16* __restrict__ Qsp, const __hip_bfloat16* __restrict__ Kt,
    const __hip_bfloat16* __restrict__ Vt, const __hip_bfloat16* __restrict__ Ksp,
    const __hip_bfloat16* __restrict__ Vsp,
    const int* __restrict__ mask_t, const int* __restrict__ mask_s,
    float* __restrict__ w_s_out, __hip_bfloat16* __restrict__ qkv_s)
{
    int blk = blockIdx.x;                  // ((b*8+h)*16 + q)
    int q = blk & 15, bh = blk >> 4, h = bh & 7, b = bh >> 3;
    __shared__ float qrow[64];
    __shared__ float wbuf[4112];
    __shared__ float red[256];
    int t = threadIdx.x;
    if (t < 64) qrow[t] = b2f(((const unsigned short*)Qsp)[(size_t)(b * 16 + q) * 512 + h * 64 + t]);
    __syncthreads();

    for (int n = t; n < 4112; n += 256) {
        const unsigned short* krow; float ma;
        if (n < 4096) {
            krow = (const unsigned short*)Kt + (size_t)(b * 4096 + n) * 512 + h * 64;
            ma = mask_t[b * 4096 + n] ? 0.f : -1e30f;
        } else {
            krow = (const unsigned short*)Ksp + (size_t)(b * 16 + (n - 4096)) * 512 + h * 64;
            ma = mask_s[b * 16 + (n - 4096)] ? 0.f : -1e30f;
        }
        float acc = 0.f;
        #pragma unroll
        for (int i = 0; i < 8; ++i) {
            U4 u; u.v = *(const uint4*)(krow + i * 8);
            #pragma unroll
            for (int k = 0; k < 8; ++k) acc += qrow[i * 8 + k] * b2f(u.u[k]);
        }
        wbuf[n] = acc * 0.125f + ma;
    }
    float lmax = -3.0e38f;
    for (int n = t; n < 4112; n += 256) lmax = fmaxf(lmax, wbuf[n]);
    red[t] = lmax; __syncthreads();
    for (int off = 128; off > 0; off >>= 1) {
        if (t < off) red[t] = fmaxf(red[t], red[t + off]);
        __syncthreads();
    }
    float gmax = red[0];
    __syncthreads();
    float lsum = 0.f;
    for (int n = t; n < 4112; n += 256) {
        float ev = __expf(wbuf[n] - gmax);
        wbuf[n] = ev;
        lsum += ev;
    }
    red[t] = lsum; __syncthreads();
    for (int off = 128; off > 0; off >>= 1) {
        if (t < off) red[t] += red[t + off];
        __syncthreads();
    }
    float inv = 1.f / red[0];
    __syncthreads();
    size_t wsb = (size_t)blk * 4112;
    for (int n = t; n < 4112; n += 256) {
        float w = wbuf[n] * inv;
        wbuf[n] = w;
        w_s_out[wsb + n] = w;
    }
    __syncthreads();
    // qkv: 64 d-lanes x 4 partial ranges of 1028 keys
    int d = t & 63, part = t >> 6;
    float acc = 0.f;
    int nstart = part * 1028, nend = nstart + 1028;
    for (int n = nstart; n < nend; ++n) {
        float w = wbuf[n];
        float v;
        if (n < 4096) v = b2f(((const unsigned short*)Vt)[(size_t)(b * 4096 + n) * 512 + h * 64 + d]);
        else          v = b2f(((const unsigned short*)Vsp)[(size_t)(b * 16 + (n - 4096)) * 512 + h * 64 + d]);
        acc += w * v;
    }
    red[t] = acc; __syncthreads();
    if (t < 64) {
        float o = red[t] + red[t + 64] + red[t + 128] + red[t + 192];
        qkv_s[(size_t)(b * 16 + q) * 512 + h * 64 + t] = __float2bfloat16(o);
    }
}

// ---------- launch ----------
extern "C" void kernel_launch(void* const* d_in, const int* in_sizes, int n_in,
                              void* d_out, int out_size, void* d_ws, size_t ws_size,
                              hipStream_t stream)
{
    const float* q_t = (const float*)d_in[0];
    const float* k_t = (const float*)d_in[1];
    const float* v_t = (const float*)d_in[2];
    const float* q_s = (const float*)d_in[3];
    const float* k_s = (const float*)d_in[4];
    const float* v_s = (const float*)d_in[5];
    const int* m_t = (const int*)d_in[6];
    const int* m_s = (const int*)d_in[7];
    const float* Wq = (const float*)d_in[8];
    const float* bq = (const float*)d_in[9];
    const float* Wk = (const float*)d_in[10];
    const float* bk = (const float*)d_in[11];
    const float* Wv = (const float*)d_in[12];
    const float* bv = (const float*)d_in[13];
    const float* Wo = (const float*)d_in[14];
    const float* bo = (const float*)d_in[15];

    char* ws = (char*)d_ws;
    size_t off = 0;
    auto alloc = [&](size_t bytes) {
        void* p = ws + off;
        off += (bytes + 255) & ~(size_t)255;
        return p;
    };
    const size_t WB = (size_t)512 * 512 * 2;     // bf16 512x512
    const size_t TB = (size_t)32768 * 512 * 2;   // bf16 32768x512
    const size_t SB = (size_t)128 * 512 * 2;     // bf16 128x512
    unsigned short* WqT = (unsigned short*)alloc(WB);
    unsigned short* WkT = (unsigned short*)alloc(WB);
    unsigned short* WvT = (unsigned short*)alloc(WB);
    unsigned short* WoT = (unsigned short*)alloc(WB);
    __hip_bfloat16* Qt   = (__hip_bfloat16*)alloc(TB);
    __hip_bfloat16* Kt   = (__hip_bfloat16*)alloc(TB);
    __hip_bfloat16* Vt   = (__hip_bfloat16*)alloc(TB);
    __hip_bfloat16* qkvT = (__hip_bfloat16*)alloc(TB);
    __hip_bfloat16* Qsp  = (__hip_bfloat16*)alloc(SB);
    __hip_bfloat16* Ksp  = (__hip_bfloat16*)alloc(SB);
    __hip_bfloat16* Vsp  = (__hip_bfloat16*)alloc(SB);
    __hip_bfloat16* qkvS = (__hip_bfloat16*)alloc(SB);

    float* out    = (float*)d_out;
    float* out_tp = out;                       // [8,512,8,512]
    float* w_t_o  = out + 16777216;            // [8,8,512,8,24]
    float* out_sp = out + 23068672;            // [8,16,512]
    float* w_s_o  = out + 23134208;            // [8,8,16,4112]

    transpose512cvt<<<dim3(16, 16), 256, 0, stream>>>(Wq, WqT);
    transpose512cvt<<<dim3(16, 16), 256, 0, stream>>>(Wk, WkT);
    transpose512cvt<<<dim3(16, 16), 256, 0, stream>>>(Wv, WvT);
    transpose512cvt<<<dim3(16, 16), 256, 0, stream>>>(Wo, WoT);

    gemm_bt<float, __hip_bfloat16><<<dim3(512, 8), 256, 0, stream>>>(q_t, WqT, bq, Qt, 32768, 512);
    gemm_bt<float, __hip_bfloat16><<<dim3(512, 8), 256, 0, stream>>>(k_t, WkT, bk, Kt, 32768, 512);
    gemm_bt<float, __hip_bfloat16><<<dim3(512, 8), 256, 0, stream>>>(v_t, WvT, bv, Vt, 32768, 512);
    gemm_bt<float, __hip_bfloat16><<<dim3(2, 8),   256, 0, stream>>>(q_s, WqT, bq, Qsp, 128, 512);
    gemm_bt<float, __hip_bfloat16><<<dim3(2, 8),   256, 0, stream>>>(k_s, WkT, bk, Ksp, 128, 512);
    gemm_bt<float, __hip_bfloat16><<<dim3(2, 8),   256, 0, stream>>>(v_s, WvT, bv, Vsp, 128, 512);

    temporal_attn<<<4096, 256, 0, stream>>>(Qt, Kt, Vt, Ksp, Vsp, m_t, m_s, w_t_o, qkvT);
    static_attn<<<1024, 256, 0, stream>>>(Qsp, Kt, Vt, Ksp, Vsp, m_t, m_s, w_s_o, qkvS);

    gemm_bt<__hip_bfloat16, float><<<dim3(512, 8), 256, 0, stream>>>(qkvT, WoT, bo, out_tp, 32768, 512);
    gemm_bt<__hip_bfloat16, float><<<dim3(2, 8),   256, 0, stream>>>(qkvS, WoT, bo, out_sp, 128, 512);
}

// Round 3
// 620.581 us; speedup vs baseline: 1.4505x; 1.4505x over previous
//
#include <hip/hip_runtime.h>
#include <hip/hip_bf16.h>

// ---------- helpers ----------
typedef __attribute__((ext_vector_type(8))) __bf16 bf16x8;
typedef __attribute__((ext_vector_type(4))) float f32x4;

__device__ __forceinline__ float b2f(unsigned short u) {
    unsigned int x = ((unsigned int)u) << 16;
    float f;
    __builtin_memcpy(&f, &x, 4);
    return f;
}
__device__ __forceinline__ unsigned short f2b(float f) {
    __hip_bfloat16 h = __float2bfloat16(f);
    unsigned short u;
    __builtin_memcpy(&u, &h, 2);
    return u;
}
union U4 { uint4 v; unsigned short u[8]; };

// ---------- 512x512 transpose + f32->bf16 convert (for W matrices) ----------
__global__ __launch_bounds__(256) void transpose512cvt(const float* __restrict__ in,
                                                       unsigned short* __restrict__ out)
{
    __shared__ float tile[32][33];
    int tx = threadIdx.x & 31, ty = threadIdx.x >> 5;
    int bx = blockIdx.x, by = blockIdx.y;
    #pragma unroll
    for (int i = 0; i < 32; i += 8)
        tile[ty + i][tx] = in[(size_t)(bx * 32 + ty + i) * 512 + by * 32 + tx];
    __syncthreads();
    #pragma unroll
    for (int i = 0; i < 32; i += 8)
        out[(size_t)(by * 32 + ty + i) * 512 + bx * 32 + tx] = f2b(tile[tx][ty + i]);
}

// ---------- GEMM 128x128 tile (m93-style): C = A[M,512] @ Bt[512,N]^T + bias ----------
// 256 threads = 4 waves in 2x2; each wave owns 64x64 = 4x4 MFMA tiles.
// CMODE: 0 = f32 token-major, 1 = bf16 token-major, 2 = bf16 head-major [b][h][n][d]
#define GPAD 40  // row stride in elems (32 + 8 pad, 80 B, 16B-aligned)

template<bool AF32, int CMODE>
__global__ __launch_bounds__(256) void gemm128(
    const void* __restrict__ Av,
    const unsigned short* __restrict__ Bt,
    const float* __restrict__ bias,
    void* __restrict__ Cv,
    int M, int N)
{
    const int K = 512;
    __shared__ __align__(16) unsigned short As[128 * GPAD];
    __shared__ __align__(16) unsigned short Bs[128 * GPAD];
    int m0 = blockIdx.x * 128, n0 = blockIdx.y * 128;
    int t = threadIdx.x;
    int wave = t >> 6, lane = t & 63, quad = lane >> 4, l16 = lane & 15;
    int wr = wave >> 1, wc = wave & 1;

    f32x4 acc[4][4];
    #pragma unroll
    for (int i = 0; i < 4; ++i)
        #pragma unroll
        for (int j = 0; j < 4; ++j) acc[i][j] = (f32x4){0.f, 0.f, 0.f, 0.f};

    int r = t >> 1, half = (t & 1) * 16;  // staging: row r, elems half..half+16

    for (int k0 = 0; k0 < K; k0 += 32) {
        U4 a0, a1;
        uint4 b0, b1;
        if constexpr (AF32) {
            const float* Ap = (const float*)Av + (size_t)(m0 + r) * K + k0 + half;
            float4 f0 = ((const float4*)Ap)[0], f1 = ((const float4*)Ap)[1];
            float4 f2 = ((const float4*)Ap)[2], f3 = ((const float4*)Ap)[3];
            a0.u[0]=f2b(f0.x); a0.u[1]=f2b(f0.y); a0.u[2]=f2b(f0.z); a0.u[3]=f2b(f0.w);
            a0.u[4]=f2b(f1.x); a0.u[5]=f2b(f1.y); a0.u[6]=f2b(f1.z); a0.u[7]=f2b(f1.w);
            a1.u[0]=f2b(f2.x); a1.u[1]=f2b(f2.y); a1.u[2]=f2b(f2.z); a1.u[3]=f2b(f2.w);
            a1.u[4]=f2b(f3.x); a1.u[5]=f2b(f3.y); a1.u[6]=f2b(f3.z); a1.u[7]=f2b(f3.w);
        } else {
            const unsigned short* Ap = (const unsigned short*)Av + (size_t)(m0 + r) * K + k0 + half;
            a0.v = ((const uint4*)Ap)[0];
            a1.v = ((const uint4*)Ap)[1];
        }
        {
            const unsigned short* Bp = Bt + (size_t)(n0 + r) * K + k0 + half;
            b0 = ((const uint4*)Bp)[0];
            b1 = ((const uint4*)Bp)[1];
        }
        __syncthreads();
        *(uint4*)&As[r * GPAD + half] = a0.v;
        *(uint4*)&As[r * GPAD + half + 8] = a1.v;
        *(uint4*)&Bs[r * GPAD + half] = b0;
        *(uint4*)&Bs[r * GPAD + half + 8] = b1;
        __syncthreads();
        bf16x8 af[4], bf[4];
        #pragma unroll
        for (int i = 0; i < 4; ++i)
            af[i] = *(const bf16x8*)&As[(wr * 64 + i * 16 + l16) * GPAD + quad * 8];
        #pragma unroll
        for (int j = 0; j < 4; ++j)
            bf[j] = *(const bf16x8*)&Bs[(wc * 64 + j * 16 + l16) * GPAD + quad * 8];
        #pragma unroll
        for (int i = 0; i < 4; ++i)
            #pragma unroll
            for (int j = 0; j < 4; ++j)
                acc[i][j] = __builtin_amdgcn_mfma_f32_16x16x32_bf16(af[i], bf[j], acc[i][j], 0, 0, 0);
    }
    // epilogue. C/D layout: col = lane&15, row = quad*4 + reg
    #pragma unroll
    for (int i = 0; i < 4; ++i) {
        #pragma unroll
        for (int j = 0; j < 4; ++j) {
            int row = m0 + wr * 64 + i * 16 + quad * 4;
            int col = n0 + wc * 64 + j * 16 + l16;
            float bc = bias[col];
            #pragma unroll
            for (int ii = 0; ii < 4; ++ii) {
                float v = acc[i][j][ii] + bc;
                int R = row + ii;
                if constexpr (CMODE == 0) {
                    ((float*)Cv)[(size_t)R * N + col] = v;
                } else if constexpr (CMODE == 1) {
                    ((unsigned short*)Cv)[(size_t)R * N + col] = f2b(v);
                } else {
                    int bb = R >> 12, n = R & 4095, hh = col >> 6, d = col & 63;
                    ((unsigned short*)Cv)[(((size_t)bb * 8 + hh) * 4096 + n) * 64 + d] = f2b(v);
                }
            }
        }
    }
}

// ---------- temporal attention: one block per (b,s) ----------
// K/V temporal now head-major [b][h][4096][64]; K/V static token-major [b*16+k][512].
__global__ __launch_bounds__(256) void temporal_attn(
    const unsigned short* __restrict__ Qt, const unsigned short* __restrict__ KH,
    const unsigned short* __restrict__ VH, const unsigned short* __restrict__ Ksp,
    const unsigned short* __restrict__ Vsp,
    const int* __restrict__ mask_t, const int* __restrict__ mask_s,
    float* __restrict__ w_t_out, unsigned short* __restrict__ qkv_t)
{
    int bs = blockIdx.x;
    int b = bs >> 9, s = bs & 511;
    __shared__ __align__(16) unsigned short sK2[64 * 72];   // [h*8+m][64]
    __shared__ __align__(16) unsigned short sKs[16 * 520];  // [k][512]
    __shared__ float wbuf[64 * 24];
    __shared__ float maskadd[24];
    int t = threadIdx.x;

    for (int idx = t; idx < 512; idx += 256) {
        int h = idx >> 6, rem = idx & 63;
        int m = rem >> 3, part = rem & 7;
        uint4 v = *(const uint4*)(KH + ((((size_t)b * 8 + h) * 4096) + s * 8 + m) * 64 + part * 8);
        *(uint4*)&sK2[(h * 8 + m) * 72 + part * 8] = v;
    }
    const uint4* Ksg = (const uint4*)(Ksp + (size_t)b * 8192);
    for (int idx = t; idx < 1024; idx += 256) {
        uint4 v = Ksg[idx];
        *(uint4*)&sKs[(idx >> 6) * 520 + (idx & 63) * 8] = v;
    }
    if (t < 8) maskadd[t] = mask_t[bs * 8 + t] ? 0.f : -1e30f;
    else if (t < 24) maskadd[t] = mask_s[b * 16 + (t - 8)] ? 0.f : -1e30f;

    int p = t >> 2, j = t & 3;       // pair p = (h,m), 4 threads per pair
    int h = p >> 3, m = p & 7;

    float qreg[64];
    {
        const uint4* qp = (const uint4*)(Qt + (size_t)bs * 4096 + (size_t)m * 512 + h * 64);
        #pragma unroll
        for (int i = 0; i < 8; ++i) {
            U4 u; u.v = qp[i];
            #pragma unroll
            for (int k = 0; k < 8; ++k) qreg[i * 8 + k] = b2f(u.u[k]);
        }
    }
    __syncthreads();

    float sc[6];
    #pragma unroll
    for (int i = 0; i < 6; ++i) {
        int n = j + i * 4;
        const unsigned short* krow = (n < 8) ? &sK2[(h * 8 + n) * 72] : &sKs[(n - 8) * 520 + h * 64];
        float acc = 0.f;
        #pragma unroll
        for (int d = 0; d < 64; ++d) acc += qreg[d] * b2f(krow[d]);
        sc[i] = acc * 0.125f + maskadd[n];
    }
    float mx = sc[0];
    #pragma unroll
    for (int i = 1; i < 6; ++i) mx = fmaxf(mx, sc[i]);
    mx = fmaxf(mx, __shfl_xor(mx, 1));
    mx = fmaxf(mx, __shfl_xor(mx, 2));
    float e[6], se = 0.f;
    #pragma unroll
    for (int i = 0; i < 6; ++i) { e[i] = __expf(sc[i] - mx); se += e[i]; }
    se += __shfl_xor(se, 1);
    se += __shfl_xor(se, 2);
    float inv = 1.f / se;
    size_t wtb = ((((size_t)b * 8 + h) * 512 + s) * 8 + m) * 24;
    #pragma unroll
    for (int i = 0; i < 6; ++i) {
        int n = j + i * 4;
        float w = e[i] * inv;
        wbuf[p * 24 + n] = w;
        w_t_out[wtb + n] = w;
    }
    __syncthreads();

    // phase 2: qkv[h,m][d0..d0+16] = sum_n w[n] * V[n][d]
    int hm = t >> 2, dc = t & 3;
    int h2 = hm >> 3, m2 = hm & 7, d0 = dc * 16;
    float acc2[16];
    #pragma unroll
    for (int i = 0; i < 16; ++i) acc2[i] = 0.f;
    const unsigned short* Vb = VH + (((size_t)(b * 8 + h2)) * 4096 + s * 8) * 64 + d0;
    #pragma unroll
    for (int n = 0; n < 8; ++n) {
        float wv = wbuf[hm * 24 + n];
        U4 a, c;
        a.v = *(const uint4*)(Vb + n * 64);
        c.v = *(const uint4*)(Vb + n * 64 + 8);
        #pragma unroll
        for (int i = 0; i < 8; ++i) { acc2[i] += wv * b2f(a.u[i]); acc2[8 + i] += wv * b2f(c.u[i]); }
    }
    const unsigned short* Vsb = Vsp + (size_t)b * 8192 + h2 * 64 + d0;
    #pragma unroll
    for (int n = 0; n < 16; ++n) {
        float wv = wbuf[hm * 24 + 8 + n];
        U4 a, c;
        a.v = *(const uint4*)(Vsb + n * 512);
        c.v = *(const uint4*)(Vsb + n * 512 + 8);
        #pragma unroll
        for (int i = 0; i < 8; ++i) { acc2[i] += wv * b2f(a.u[i]); acc2[8 + i] += wv * b2f(c.u[i]); }
    }
    unsigned short* op = qkv_t + (size_t)bs * 4096 + (size_t)m2 * 512 + h2 * 64 + d0;
    #pragma unroll
    for (int i = 0; i < 16; ++i) op[i] = f2b(acc2[i]);
}

// ---------- static attention S1: fused scores + exp + PV, chunked ----------
// grid = 8 chunks x 64 (b,h). Keys processed in 32-wide steps; 129 steps total
// (step 128 = the 16 static keys). No max-subtraction (|s| <= ~8, exp safe in f32).
__global__ __launch_bounds__(256) void static_attn_s1(
    const unsigned short* __restrict__ Qsp, const unsigned short* __restrict__ KH,
    const unsigned short* __restrict__ VH, const unsigned short* __restrict__ Ksp,
    const unsigned short* __restrict__ Vsp,
    const int* __restrict__ mask_t, const int* __restrict__ mask_s,
    float* __restrict__ w_s, float* __restrict__ Ppart, float* __restrict__ Lpart)
{
    int blk = blockIdx.x;
    int bh = blk & 63, c = blk >> 6;
    int b = bh >> 3, h = bh & 7;
    __shared__ __align__(16) unsigned short Klds[32 * 72];  // [key][64] (+pad)
    __shared__ __align__(16) unsigned short Vlds[64 * 40];  // [d][key]  (+pad)
    __shared__ __align__(16) unsigned short Plds[16 * 40];  // [q][key]  (+pad)
    __shared__ float maskv[32];
    __shared__ float sL[2][16];
    int t = threadIdx.x, wave = t >> 6, lane = t & 63, quad = lane >> 4, l16 = lane & 15;

    // Q fragments (A-operand: m=l16 -> q, k=quad*8+j -> d)
    bf16x8 qf0 = *(const bf16x8*)(Qsp + ((size_t)(b * 16 + l16)) * 512 + h * 64 + quad * 8);
    bf16x8 qf1 = *(const bf16x8*)(Qsp + ((size_t)(b * 16 + l16)) * 512 + h * 64 + 32 + quad * 8);

    f32x4 pacc = (f32x4){0.f, 0.f, 0.f, 0.f};
    float Lacc[4] = {0.f, 0.f, 0.f, 0.f};
    int d0 = wave * 16;
    int sub = wave >> 1;
    int sr = t >> 3, spart = t & 7;
    int s0 = c * 16, s1 = (c == 7) ? 129 : (s0 + 16);

    for (int st = s0; st < s1; ++st) {
        int key0 = st * 32;
        // ---- stage K row-major, V transposed, masks ----
        int kk = key0 + sr;
        uint4 kv = {0, 0, 0, 0}, vv = {0, 0, 0, 0};
        if (kk < 4096) {
            kv = *(const uint4*)(KH + (((size_t)bh) * 4096 + kk) * 64 + spart * 8);
            vv = *(const uint4*)(VH + (((size_t)bh) * 4096 + kk) * 64 + spart * 8);
        } else if (kk < 4112) {
            kv = *(const uint4*)(Ksp + ((size_t)(b * 16 + kk - 4096)) * 512 + h * 64 + spart * 8);
            vv = *(const uint4*)(Vsp + ((size_t)(b * 16 + kk - 4096)) * 512 + h * 64 + spart * 8);
        }
        __syncthreads();   // prior PV reads done before overwriting LDS
        *(uint4*)&Klds[sr * 72 + spart * 8] = kv;
        {
            U4 u; u.v = vv;
            #pragma unroll
            for (int ii = 0; ii < 8; ++ii) Vlds[(spart * 8 + ii) * 40 + sr] = u.u[ii];
        }
        if (t < 32) {
            int k2 = key0 + t;
            float ma = -1e30f;
            if (k2 < 4096) ma = mask_t[b * 4096 + k2] ? 0.f : -1e30f;
            else if (k2 < 4112) ma = mask_s[b * 16 + k2 - 4096] ? 0.f : -1e30f;
            maskv[t] = ma;
        }
        __syncthreads();
        // ---- scores (waves 0,2): 16-key subtile each ----
        if ((wave & 1) == 0) {
            bf16x8 kf0 = *(const bf16x8*)&Klds[(sub * 16 + l16) * 72 + quad * 8];
            bf16x8 kf1 = *(const bf16x8*)&Klds[(sub * 16 + l16) * 72 + 32 + quad * 8];
            f32x4 sc = (f32x4){0.f, 0.f, 0.f, 0.f};
            sc = __builtin_amdgcn_mfma_f32_16x16x32_bf16(qf0, kf0, sc, 0, 0, 0);
            sc = __builtin_amdgcn_mfma_f32_16x16x32_bf16(qf1, kf1, sc, 0, 0, 0);
            float ma = maskv[sub * 16 + l16];
            size_t wbase = (((size_t)bh) * 16 + quad * 4) * 4112 + key0 + sub * 16 + l16;
            #pragma unroll
            for (int i = 0; i < 4; ++i) {
                float sv = sc[i] * 0.125f + ma;
                float w = __expf(sv);
                Lacc[i] += w;
                w_s[wbase + (size_t)i * 4112] = w;   // unnormalized; S4 rescales
                Plds[(quad * 4 + i) * 40 + sub * 16 + l16] = f2b(w);
            }
        }
        __syncthreads();
        // ---- PV: every wave owns a 16-wide d-tile ----
        bf16x8 pf = *(const bf16x8*)&Plds[l16 * 40 + quad * 8];
        bf16x8 vf = *(const bf16x8*)&Vlds[(d0 + l16) * 40 + quad * 8];
        pacc = __builtin_amdgcn_mfma_f32_16x16x32_bf16(pf, vf, pacc, 0, 0, 0);
    }

    // reduce L across the 16 key-lanes (waves 0,2 only)
    if ((wave & 1) == 0) {
        #pragma unroll
        for (int i = 0; i < 4; ++i) {
            float v = Lacc[i];
            v += __shfl_xor(v, 1);
            v += __shfl_xor(v, 2);
            v += __shfl_xor(v, 4);
            v += __shfl_xor(v, 8);
            Lacc[i] = v;
        }
        if (l16 == 0) {
            #pragma unroll
            for (int i = 0; i < 4; ++i) sL[wave >> 1][quad * 4 + i] = Lacc[i];
        }
    }
    // PV partials
    size_t pbase = ((size_t)(bh * 8 + c) * 16 + quad * 4) * 64 + d0 + l16;
    #pragma unroll
    for (int i = 0; i < 4; ++i) Ppart[pbase + (size_t)i * 64] = pacc[i];
    __syncthreads();
    if (t < 16) Lpart[(bh * 8 + c) * 16 + t] = sL[0][t] + sL[1][t];
}

// ---------- static attention S4: combine chunk partials + normalize ----------
__global__ __launch_bounds__(256) void static_attn_s4(
    const float* __restrict__ Ppart, const float* __restrict__ Lpart,
    float* __restrict__ w_s, unsigned short* __restrict__ qkvS)
{
    int bh = blockIdx.x, b = bh >> 3, h = bh & 7;
    __shared__ float invL[16];
    int t = threadIdx.x;
    if (t < 16) {
        float L = 0.f;
        #pragma unroll
        for (int cc = 0; cc < 8; ++cc) L += Lpart[(bh * 8 + cc) * 16 + t];
        invL[t] = 1.f / L;
    }
    __syncthreads();
    #pragma unroll
    for (int i = 0; i < 4; ++i) {
        int idx = t + i * 256;
        int q = idx >> 6, d = idx & 63;
        float s = 0.f;
        #pragma unroll
        for (int cc = 0; cc < 8; ++cc) s += Ppart[((size_t)(bh * 8 + cc) * 16 + q) * 64 + d];
        qkvS[((size_t)(b * 16 + q)) * 512 + h * 64 + d] = f2b(s * invL[q]);
    }
    size_t base = (size_t)bh * 16 * 4112;
    for (int q = 0; q < 16; ++q) {
        float il = invL[q];
        for (int kk = t; kk < 4112; kk += 256) w_s[base + q * 4112 + kk] *= il;
    }
}

// ---------- launch ----------
extern "C" void kernel_launch(void* const* d_in, const int* in_sizes, int n_in,
                              void* d_out, int out_size, void* d_ws, size_t ws_size,
                              hipStream_t stream)
{
    const float* q_t = (const float*)d_in[0];
    const float* k_t = (const float*)d_in[1];
    const float* v_t = (const float*)d_in[2];
    const float* q_s = (const float*)d_in[3];
    const float* k_s = (const float*)d_in[4];
    const float* v_s = (const float*)d_in[5];
    const int* m_t = (const int*)d_in[6];
    const int* m_s = (const int*)d_in[7];
    const float* Wq = (const float*)d_in[8];
    const float* bq = (const float*)d_in[9];
    const float* Wk = (const float*)d_in[10];
    const float* bk = (const float*)d_in[11];
    const float* Wv = (const float*)d_in[12];
    const float* bv = (const float*)d_in[13];
    const float* Wo = (const float*)d_in[14];
    const float* bo = (const float*)d_in[15];

    char* ws = (char*)d_ws;
    size_t off = 0;
    auto alloc = [&](size_t bytes) {
        void* p = ws + off;
        off += (bytes + 255) & ~(size_t)255;
        return p;
    };
    const size_t WB = (size_t)512 * 512 * 2;     // bf16 512x512
    const size_t TB = (size_t)32768 * 512 * 2;   // bf16 32768x512
    const size_t SB = (size_t)128 * 512 * 2;     // bf16 128x512
    unsigned short* WqT = (unsigned short*)alloc(WB);
    unsigned short* WkT = (unsigned short*)alloc(WB);
    unsigned short* WvT = (unsigned short*)alloc(WB);
    unsigned short* WoT = (unsigned short*)alloc(WB);
    unsigned short* Qt   = (unsigned short*)alloc(TB);  // token-major
    unsigned short* KH   = (unsigned short*)alloc(TB);  // head-major [b][h][n][d]
    unsigned short* VH   = (unsigned short*)alloc(TB);  // head-major
    unsigned short* qkvT = (unsigned short*)alloc(TB);  // token-major
    unsigned short* Qsp  = (unsigned short*)alloc(SB);
    unsigned short* Ksp  = (unsigned short*)alloc(SB);
    unsigned short* Vsp  = (unsigned short*)alloc(SB);
    unsigned short* qkvS = (unsigned short*)alloc(SB);
    float* Ppart = (float*)alloc((size_t)64 * 8 * 16 * 64 * 4);  // [bh][chunk][q][d]
    float* Lpart = (float*)alloc((size_t)64 * 8 * 16 * 4);       // [bh][chunk][q]

    float* out    = (float*)d_out;
    float* out_tp = out;                       // [8,512,8,512]
    float* w_t_o  = out + 16777216;            // [8,8,512,8,24]
    float* out_sp = out + 23068672;            // [8,16,512]
    float* w_s_o  = out + 23134208;            // [8,8,16,4112]

    transpose512cvt<<<dim3(16, 16), 256, 0, stream>>>(Wq, WqT);
    transpose512cvt<<<dim3(16, 16), 256, 0, stream>>>(Wk, WkT);
    transpose512cvt<<<dim3(16, 16), 256, 0, stream>>>(Wv, WvT);
    transpose512cvt<<<dim3(16, 16), 256, 0, stream>>>(Wo, WoT);

    gemm128<true, 1><<<dim3(256, 4), 256, 0, stream>>>(q_t, WqT, bq, Qt, 32768, 512);
    gemm128<true, 2><<<dim3(256, 4), 256, 0, stream>>>(k_t, WkT, bk, KH, 32768, 512);
    gemm128<true, 2><<<dim3(256, 4), 256, 0, stream>>>(v_t, WvT, bv, VH, 32768, 512);
    gemm128<true, 1><<<dim3(1, 4),   256, 0, stream>>>(q_s, WqT, bq, Qsp, 128, 512);
    gemm128<true, 1><<<dim3(1, 4),   256, 0, stream>>>(k_s, WkT, bk, Ksp, 128, 512);
    gemm128<true, 1><<<dim3(1, 4),   256, 0, stream>>>(v_s, WvT, bv, Vsp, 128, 512);

    temporal_attn<<<4096, 256, 0, stream>>>(Qt, KH, VH, Ksp, Vsp, m_t, m_s, w_t_o, qkvT);
    static_attn_s1<<<512, 256, 0, stream>>>(Qsp, KH, VH, Ksp, Vsp, m_t, m_s, w_s_o, Ppart, Lpart);
    static_attn_s4<<<64, 256, 0, stream>>>(Ppart, Lpart, w_s_o, qkvS);

    gemm128<false, 0><<<dim3(256, 4), 256, 0, stream>>>(qkvT, WoT, bo, out_tp, 32768, 512);
    gemm128<false, 0><<<dim3(1, 4),   256, 0, stream>>>(qkvS, WoT, bo, out_sp, 128, 512);
}